// Round 3
// baseline (1045.049 us; speedup 1.0000x reference)
//
#include <hip/hip_runtime.h>

// TT-LSTM: B=64, T=1024, D=H=256, F=16, R=16, NG=4.
// ws layout (floats):
//   A1ihT [64][256]  @ 0       ([g*16+s][m*16+n], composed g0*g1 for ih)
//   A1hT  [64][256]  @ 16384   (same for hh)
//   C2ih  [64][256]  @ 32768   ([g*16+s][o*16+p], composed g2*g3 for ih)
//   C2h   [64][256]  @ 49152
//   biasS [4][256]   @ 65536   (ih_bias + hh_bias)
//   T2ih  [65536][64]@ 66560   (first-stage ih contraction for all rows)

#define WS_A1I 0
#define WS_A1H 16384
#define WS_C2I 32768
#define WS_C2H 49152
#define WS_BIAS 65536
#define WS_T2 66560

typedef float v2f __attribute__((ext_vector_type(2)));

// Packed fp32 FMA: 2 FMAs/instruction.
__device__ __forceinline__ v2f pk_fma(v2f a, v2f b, v2f c) {
    v2f d;
    asm("v_pk_fma_f32 %0, %1, %2, %3" : "=v"(d) : "v"(a), "v"(b), "v"(c));
    return d;
}

// Barrier draining LDS only (lgkmcnt), NOT global loads/stores (vmcnt).
__device__ __forceinline__ void bar_lds() {
    asm volatile("s_waitcnt lgkmcnt(0)\n\ts_barrier" ::: "memory");
}

// DPP helpers: cross-lane at VALU rate (no DS pipe).
// row_shr:n = 0x110|n ; quad_perm(k,k,k,k) = k*0x55. bound_ctrl=1 -> 0 fill.
template <int CTRL>
__device__ __forceinline__ float dpp_add(float v) {
    int s = __builtin_amdgcn_update_dpp(0, __float_as_int(v), CTRL, 0xF, 0xF, true);
    return v + __int_as_float(s);
}
template <int CTRL>
__device__ __forceinline__ float dpp_bcast(float v) {
    int s = __builtin_amdgcn_update_dpp(0, __float_as_int(v), CTRL, 0xF, 0xF, true);
    return __int_as_float(s);
}

// ---------------- K0: compose TT cores ----------------
__global__ void k_compose(const float* __restrict__ g0i, const float* __restrict__ g1i,
                          const float* __restrict__ g2i, const float* __restrict__ g3i,
                          const float* __restrict__ bi,
                          const float* __restrict__ g0h, const float* __restrict__ g1h,
                          const float* __restrict__ g2h, const float* __restrict__ g3h,
                          const float* __restrict__ bh,
                          float* __restrict__ ws) {
    int id = blockIdx.x * 256 + threadIdx.x;
    if (id < 16384) {
        int g = id >> 12, s = (id >> 8) & 15, mn = id & 255;
        int m = mn >> 4, n = mn & 15;
        float aI = 0.f, aH = 0.f;
        for (int r = 0; r < 16; ++r) {
            aI += g0i[(g * 16 + m) * 16 + r] * g1i[((g * 16 + r) * 16 + n) * 16 + s];
            aH += g0h[(g * 16 + m) * 16 + r] * g1h[((g * 16 + r) * 16 + n) * 16 + s];
        }
        ws[WS_A1I + (g * 16 + s) * 256 + mn] = aI;
        ws[WS_A1H + (g * 16 + s) * 256 + mn] = aH;
    } else if (id < 32768) {
        int id2 = id - 16384;
        int g = id2 >> 12, s = (id2 >> 8) & 15, j = id2 & 255;
        int o = j >> 4, p = j & 15;
        float aI = 0.f, aH = 0.f;
        for (int t = 0; t < 16; ++t) {
            aI += g2i[((g * 16 + s) * 16 + o) * 16 + t] * g3i[(g * 16 + t) * 16 + p];
            aH += g2h[((g * 16 + s) * 16 + o) * 16 + t] * g3h[(g * 16 + t) * 16 + p];
        }
        ws[WS_C2I + (g * 16 + s) * 256 + j] = aI;
        ws[WS_C2H + (g * 16 + s) * 256 + j] = aH;
    } else if (id < 33792) {
        int id2 = id - 32768;
        ws[WS_BIAS + id2] = bi[id2] + bh[id2];
    }
}

// ---------------- K1: T2 = X @ A1ihT ----------------
// r3 rewrite. Old design read 8 ds_read_b128 per 32 pk_fma; LDS return BW
// (one 128B/clk pipe per CU, wave-b128 = 1KB >= 8clk even broadcast) made it
// DS-pipe bound (~130us). New design:
//  - one WAVE per 64-row tile (grid 256 x 4 waves = 1024 tiles, 1 wave/SIMD);
//    no __syncthreads anywhere (each wave owns a private LDS slice).
//  - lane = row. A1ih read via wave-uniform s_load (scalar pipe, zero DS).
//  - X transposed once through LDS: stage 16KB chunk coalesced (256B
//    segments), read b64 per k-pair at stride 66 floats (bank =
//    (2*lane+2kp)&31 -> 4-way = ~1.6x on a 4clk op, negligible).
//  - acc[64] per lane = the lane's full T2 row. 16K v_fmac_f32 v,s,v
//    per wave = ~32Kcy/SIMD: VALU-issue bound, ~14us + staging.
__global__ __launch_bounds__(256, 2) void k_t2ih(const float* __restrict__ x,
                                                 const float* __restrict__ ws,
                                                 float* __restrict__ T2) {
    __shared__ __align__(16) float Xc[4][64 * 66 + 8];
    const int tid  = threadIdx.x;
    const int wv   = tid >> 6;
    const int lane = tid & 63;
    const long tile = (long)blockIdx.x * 4 + wv;     // 0..1023
    const long r0   = tile * 64;
    float* Xw = Xc[wv];

    const float4* X4g = (const float4*)x;            // row stride 64 float4
    const float* A = ws + WS_A1I;                    // [u][k] row-major

    float acc[64];
#pragma unroll
    for (int u = 0; u < 64; ++u) acc[u] = 0.f;

    for (int kc = 0; kc < 4; ++kc) {
        // stage chunk k = [kc*64, kc*64+64) for rows r0..r0+63, transposed
        // into [row][66-padded]; coalesced 256B global segments.
#pragma unroll
        for (int it = 0; it < 16; ++it) {
            int row = it * 4 + (lane >> 4);
            int c4  = lane & 15;
            float4 v = X4g[(r0 + row) * 64 + kc * 16 + c4];
            float* d = &Xw[row * 66 + c4 * 4];
            d[0] = v.x; d[1] = v.y; d[2] = v.z; d[3] = v.w;
        }
        // intra-wave only: compiler inserts lgkmcnt before dependent reads.
        for (int kp = 0; kp < 32; ++kp) {
            v2f xp = *(const v2f*)&Xw[lane * 66 + 2 * kp];
            const float* Ak = A + kc * 64 + 2 * kp;  // uniform -> s_load
#pragma unroll
            for (int u = 0; u < 64; ++u) {
                acc[u] += xp.x * Ak[u * 256] + xp.y * Ak[u * 256 + 1];
            }
        }
    }
    // lane's T2 row is contiguous: 16 float4 stores.
    float4* T24 = (float4*)T2;
#pragma unroll
    for (int u4 = 0; u4 < 16; ++u4) {
        float4 o;
        o.x = acc[4 * u4 + 0]; o.y = acc[4 * u4 + 1];
        o.z = acc[4 * u4 + 2]; o.w = acc[4 * u4 + 3];
        T24[(r0 + lane) * 16 + u4] = o;
    }
}

// ---------------- K2: recurrent LSTM ----------------
// Reverted to the r1 structure (741us): ih partial stays in the CD phase
// where it overlaps the th4 LDS-read latency (r2 moved it pre-barrier and
// regressed to 798us: phase 1 lengthened, phase 2 became pure serial
// latency). 64 blocks x 1024 threads (16 waves, 4/SIMD), 2 barriers/step,
// zero DS-pipe cross-lane ops (DPP reductions/gathers at VALU rate).
// hS transposed layout: float4 slot kk*16+sub = h[16*sub+4*kk..+3]
// -> AB reads bank-base 4*sub mod 32 = true 2-way (free).
__global__ __launch_bounds__(1024, 4) void k_lstm(const float* __restrict__ ws,
                                                  const float* __restrict__ T2,
                                                  float* __restrict__ out) {
    __shared__ __align__(16) float hS[256];
    __shared__ __align__(16) float t2hS[64];
    __shared__ __align__(16) float t2iS[2][64];

    const int tid  = threadIdx.x;
    const int w    = tid >> 6;
    const int lane = tid & 63;
    const int b    = blockIdx.x;

    // ---- AB weights: a1p[8] (v2f pairs) = A1h[u][sub*16 .. sub*16+16) ----
    const int uab = 4 * w + (lane >> 4);
    const int sub = lane & 15;
    v2f a1p[8];
    {
        const float4* A1h4 = (const float4*)(ws + WS_A1H);
#pragma unroll
        for (int kk = 0; kk < 4; ++kk) {
            float4 v = A1h4[uab * 64 + sub * 4 + kk];
            a1p[2 * kk + 0] = (v2f){v.x, v.y};
            a1p[2 * kk + 1] = (v2f){v.z, v.w};
        }
    }

    // ---- CD weights: jj=lane>>2, gate g=lane&3, hidden j=16w+jj ----
    const int jj = lane >> 2;
    const int g  = lane & 3;
    const int j  = 16 * w + jj;
    v2f c2hp[8], c2ip[8];
#pragma unroll
    for (int qq = 0; qq < 4; ++qq) {
        float h0 = ws[WS_C2H + (16 * g + 4 * qq + 0) * 256 + j];
        float h1 = ws[WS_C2H + (16 * g + 4 * qq + 1) * 256 + j];
        float h2 = ws[WS_C2H + (16 * g + 4 * qq + 2) * 256 + j];
        float h3 = ws[WS_C2H + (16 * g + 4 * qq + 3) * 256 + j];
        float i0 = ws[WS_C2I + (16 * g + 4 * qq + 0) * 256 + j];
        float i1 = ws[WS_C2I + (16 * g + 4 * qq + 1) * 256 + j];
        float i2 = ws[WS_C2I + (16 * g + 4 * qq + 2) * 256 + j];
        float i3 = ws[WS_C2I + (16 * g + 4 * qq + 3) * 256 + j];
        c2hp[2 * qq + 0] = (v2f){h0, h1};
        c2hp[2 * qq + 1] = (v2f){h2, h3};
        c2ip[2 * qq + 0] = (v2f){i0, i1};
        c2ip[2 * qq + 1] = (v2f){i2, i3};
    }
    float bias = ws[WS_BIAS + g * 256 + j];
    const float am = (g == 2) ? 2.0f : 1.0f;            // tanh vs sigmoid
    const float as = 1.442695040888963f * am;

#pragma unroll
    for (int i = 0; i < 8; ++i)
        asm volatile("" : "+v"(a1p[i]), "+v"(c2hp[i]), "+v"(c2ip[i]));

    // transposed hS slot for writer (g==0): word 64*(jj>>2) + 4*w + (jj&3)
    const int hw = ((jj >> 2) << 6) + (w << 2) + (jj & 3);

    float c = 0.f, h_last = 0.f;
    if (tid < 256) hS[tid] = 0.f;
    const float* T2b = T2 + (long)b * 1024 * 64;
    const float4* T2b4 = (const float4*)T2b;
    float4 preA = make_float4(0.f, 0.f, 0.f, 0.f);
    float4 preB = make_float4(0.f, 0.f, 0.f, 0.f);
    if (tid < 16) {
        ((float4*)t2iS[0])[tid] = T2b4[tid];
        preA = T2b4[16 + tid];                          // T2[t=1]
    }
    bar_lds();

    float* outB = out + (long)b * 1024 * 256;
    const float4* hS4 = (const float4*)hS;
    const float4* th4 = (const float4*)t2hS;

    auto body = [&](int t, float4& preW, float4& preL) {
        // ---- AB (packed) ----
        v2f sA = (v2f){0.f, 0.f}, sB = (v2f){0.f, 0.f};
#pragma unroll
        for (int kk = 0; kk < 4; ++kk) {
            float4 hv = hS4[kk * 16 + sub];             // 2-way bcast, free
            sA = pk_fma((v2f){hv.x, hv.y}, a1p[2 * kk + 0], sA);
            sB = pk_fma((v2f){hv.z, hv.w}, a1p[2 * kk + 1], sB);
        }
        float tv = (sA.x + sA.y) + (sB.x + sB.y);
        // stage next t2i + prefetch (independent; overlaps DPP chain)
        if ((tid < 16) && (t + 1 < 1024))
            ((float4*)t2iS[(t + 1) & 1])[tid] = preW;
        if ((tid < 16) && (t + 2 < 1024))
            preL = T2b4[(t + 2) * 16 + tid];
        // DPP sum over 16-lane row -> total in sub==15 (VALU rate)
        tv = dpp_add<0x111>(tv);   // row_shr:1
        tv = dpp_add<0x112>(tv);   // row_shr:2
        tv = dpp_add<0x114>(tv);   // row_shr:4
        tv = dpp_add<0x118>(tv);   // row_shr:8
        if (sub == 15) t2hS[uab] = tv;

        bar_lds();  // 1: t2hS + t2iS[(t+1)&1] ready

        // ---- CD + cell (packed, 2 interleaved chains) ----
        const float4* ti4 = (const float4*)t2iS[t & 1];
        v2f aH = (v2f){bias, 0.f}, aL = (v2f){0.f, 0.f};
#pragma unroll
        for (int qq = 0; qq < 4; ++qq) {
            float4 th = th4[g * 4 + qq];                // 2-way bcast, free
            float4 ti = ti4[g * 4 + qq];
            aH = pk_fma((v2f){th.x, th.y}, c2hp[2 * qq + 0], aH);
            aL = pk_fma((v2f){th.z, th.w}, c2hp[2 * qq + 1], aL);
            aH = pk_fma((v2f){ti.x, ti.y}, c2ip[2 * qq + 0], aH);
            aL = pk_fma((v2f){ti.z, ti.w}, c2ip[2 * qq + 1], aL);
        }
        float acc = (aH.x + aH.y) + (aL.x + aL.y);
        // unified activation: sigmoid(x)=1-1/(1+e^x), tanh(x)=1-2/(1+e^2x)
        float e   = __builtin_amdgcn_exp2f(as * acc);
        float act = 1.0f - am * __builtin_amdgcn_rcpf(1.0f + e);
        // gather i,f,g,o within the quad via DPP broadcasts
        float gi = dpp_bcast<0x00>(act);
        float gf = dpp_bcast<0x55>(act);
        float gg = dpp_bcast<0xAA>(act);
        float go = dpp_bcast<0xFF>(act);
        c = gf * c + gi * gg;
        float e2 = __builtin_amdgcn_exp2f(2.885390081777926f * c);
        float th_ = 1.0f - 2.0f * __builtin_amdgcn_rcpf(1.0f + e2);
        float h = go * th_;
        h_last = h;
        if (g == 0) {
            hS[hw] = h;                                 // 4-way write, ~free
            outB[t * 256 + j] = h;                      // never drained
        }

        bar_lds();  // 2: hS ready for next AB
    };

    for (int t = 0; t < 1024; t += 2) {
        body(t, preA, preB);
        body(t + 1, preB, preA);
    }

    if (g == 0) {
        out[16777216 + b * 256 + j] = h_last;
        out[16777216 + 16384 + b * 256 + j] = c;
    }
}

extern "C" void kernel_launch(void* const* d_in, const int* in_sizes, int n_in,
                              void* d_out, int out_size, void* d_ws, size_t ws_size,
                              hipStream_t stream) {
    const float* x     = (const float*)d_in[0];
    const float* ih_g0 = (const float*)d_in[1];
    const float* ih_g1 = (const float*)d_in[2];
    const float* ih_g2 = (const float*)d_in[3];
    const float* ih_g3 = (const float*)d_in[4];
    const float* ih_b  = (const float*)d_in[5];
    const float* hh_g0 = (const float*)d_in[6];
    const float* hh_g1 = (const float*)d_in[7];
    const float* hh_g2 = (const float*)d_in[8];
    const float* hh_g3 = (const float*)d_in[9];
    const float* hh_b  = (const float*)d_in[10];
    float* out = (float*)d_out;
    float* ws  = (float*)d_ws;

    k_compose<<<132, 256, 0, stream>>>(ih_g0, ih_g1, ih_g2, ih_g3, ih_b,
                                       hh_g0, hh_g1, hh_g2, hh_g3, hh_b, ws);
    k_t2ih<<<256, 256, 0, stream>>>(x, ws, ws + WS_T2);
    k_lstm<<<64, 1024, 0, stream>>>(ws, ws + WS_T2, out);
}

// Round 4
// 844.972 us; speedup vs baseline: 1.2368x; 1.2368x over previous
//
#include <hip/hip_runtime.h>

// TT-LSTM: B=64, T=1024, D=H=256, F=16, R=16, NG=4.
// ws layout (floats):
//   A1ihT [64][256]  @ 0       ([g*16+s][m*16+n], composed g0*g1 for ih)
//   A1hT  [64][256]  @ 16384   (same for hh)
//   C2ih  [64][256]  @ 32768   ([g*16+s][o*16+p], composed g2*g3 for ih)
//   C2h   [64][256]  @ 49152
//   biasS [4][256]   @ 65536   (ih_bias + hh_bias)
//   T2ih  [65536][64]@ 66560   (first-stage ih contraction for all rows)

#define WS_A1I 0
#define WS_A1H 16384
#define WS_C2I 32768
#define WS_C2H 49152
#define WS_BIAS 65536
#define WS_T2 66560

typedef float v2f __attribute__((ext_vector_type(2)));

// Packed fp32 FMA: 2 FMAs/instruction.
__device__ __forceinline__ v2f pk_fma(v2f a, v2f b, v2f c) {
    v2f d;
    asm("v_pk_fma_f32 %0, %1, %2, %3" : "=v"(d) : "v"(a), "v"(b), "v"(c));
    return d;
}

// Barrier draining LDS only (lgkmcnt), NOT global loads/stores (vmcnt).
__device__ __forceinline__ void bar_lds() {
    asm volatile("s_waitcnt lgkmcnt(0)\n\ts_barrier" ::: "memory");
}

// DPP helpers: cross-lane at VALU rate (no DS pipe).
// row_shr:n = 0x110|n ; quad_perm(k,k,k,k) = k*0x55. bound_ctrl=1 -> 0 fill.
template <int CTRL>
__device__ __forceinline__ float dpp_add(float v) {
    int s = __builtin_amdgcn_update_dpp(0, __float_as_int(v), CTRL, 0xF, 0xF, true);
    return v + __int_as_float(s);
}
template <int CTRL>
__device__ __forceinline__ float dpp_bcast(float v) {
    int s = __builtin_amdgcn_update_dpp(0, __float_as_int(v), CTRL, 0xF, 0xF, true);
    return __int_as_float(s);
}

// ---------------- K0: compose TT cores ----------------
__global__ void k_compose(const float* __restrict__ g0i, const float* __restrict__ g1i,
                          const float* __restrict__ g2i, const float* __restrict__ g3i,
                          const float* __restrict__ bi,
                          const float* __restrict__ g0h, const float* __restrict__ g1h,
                          const float* __restrict__ g2h, const float* __restrict__ g3h,
                          const float* __restrict__ bh,
                          float* __restrict__ ws) {
    int id = blockIdx.x * 256 + threadIdx.x;
    if (id < 16384) {
        int g = id >> 12, s = (id >> 8) & 15, mn = id & 255;
        int m = mn >> 4, n = mn & 15;
        float aI = 0.f, aH = 0.f;
        for (int r = 0; r < 16; ++r) {
            aI += g0i[(g * 16 + m) * 16 + r] * g1i[((g * 16 + r) * 16 + n) * 16 + s];
            aH += g0h[(g * 16 + m) * 16 + r] * g1h[((g * 16 + r) * 16 + n) * 16 + s];
        }
        ws[WS_A1I + (g * 16 + s) * 256 + mn] = aI;
        ws[WS_A1H + (g * 16 + s) * 256 + mn] = aH;
    } else if (id < 32768) {
        int id2 = id - 16384;
        int g = id2 >> 12, s = (id2 >> 8) & 15, j = id2 & 255;
        int o = j >> 4, p = j & 15;
        float aI = 0.f, aH = 0.f;
        for (int t = 0; t < 16; ++t) {
            aI += g2i[((g * 16 + s) * 16 + o) * 16 + t] * g3i[(g * 16 + t) * 16 + p];
            aH += g2h[((g * 16 + s) * 16 + o) * 16 + t] * g3h[(g * 16 + t) * 16 + p];
        }
        ws[WS_C2I + (g * 16 + s) * 256 + j] = aI;
        ws[WS_C2H + (g * 16 + s) * 256 + j] = aH;
    } else if (id < 33792) {
        int id2 = id - 32768;
        ws[WS_BIAS + id2] = bi[id2] + bh[id2];
    }
}

// ---------------- K1: T2ih = X @ A1ih ----------------
// Reverted verbatim to the r1 version (measured ~123us, the best of the 4
// variants tried: r0 128KB/8-way=164, r1 64KB/2-way=123, r2 32KB/4blk=136,
// r3 scalar-load=~300). r3 post-mortem: 8192 s_loads/wave at 1024B stride
// (every load a distinct K$ line) with 1 wave/SIMD = unhidden scalar-latency
// chain.
__global__ __launch_bounds__(256, 2) void k_t2ih(const float* __restrict__ x,
                                                 const float* __restrict__ ws,
                                                 float* __restrict__ T2) {
    __shared__ __align__(16) float Xs[64 * 128];
    __shared__ __align__(16) float As[64 * 128];
    const int tid = threadIdx.x;
    const long r0 = (long)blockIdx.x * 64;
    const int ro = tid & 15;
    const int q  = tid >> 4;

    const float4* X4g = (const float4*)x;            // row stride 64 float4
    const float4* A4  = (const float4*)(ws + WS_A1I);
    float4* Xs4 = (float4*)Xs;                       // 32 float4 per row
    float4* As4 = (float4*)As;

    v2f acc2[4][4];
#pragma unroll
    for (int i = 0; i < 4; ++i)
#pragma unroll
        for (int j = 0; j < 4; ++j) acc2[i][j] = (v2f){0.f, 0.f};

    for (int half = 0; half < 2; ++half) {
        __syncthreads();  // WAR vs previous half's reads (no-op cost at half=0)
#pragma unroll
        for (int k = 0; k < 8; ++k) {
            int idx = k * 256 + tid;                 // 0..2047
            int row = idx >> 5, c = idx & 31;
            int sw = (row << 5) | (c ^ ((row >> 2) & 15));
            Xs4[sw] = X4g[(r0 + row) * 64 + half * 32 + c];
            As4[sw] = A4[row * 64 + half * 32 + c];
        }
        __syncthreads();

#pragma unroll 4
        for (int mn4 = 0; mn4 < 32; ++mn4) {
            float4 a[4], xv[4];
#pragma unroll
            for (int j = 0; j < 4; ++j) {
                int row = ro * 4 + j;                // row>>2 == ro
                a[j] = As4[(row << 5) | (mn4 ^ ro)];
            }
#pragma unroll
            for (int i = 0; i < 4; ++i) {
                int row = q * 4 + i;                 // row>>2 == q
                xv[i] = Xs4[(row << 5) | (mn4 ^ q)];
            }
#pragma unroll
            for (int i = 0; i < 4; ++i)
#pragma unroll
                for (int j = 0; j < 4; ++j) {
                    acc2[i][j] = pk_fma((v2f){xv[i].x, xv[i].y},
                                        (v2f){a[j].x, a[j].y}, acc2[i][j]);
                    acc2[i][j] = pk_fma((v2f){xv[i].z, xv[i].w},
                                        (v2f){a[j].z, a[j].w}, acc2[i][j]);
                }
        }
    }
#pragma unroll
    for (int i = 0; i < 4; ++i)
#pragma unroll
        for (int j = 0; j < 4; ++j)
            T2[(r0 + q * 4 + i) * 64 + ro * 4 + j] = acc2[i][j].x + acc2[i][j].y;
}

// ---------------- K2: recurrent LSTM ----------------
// r4 restructure: 64 blocks x 512 threads (8 waves, 2/SIMD), 2 outputs per
// thread. Rationale (recalibrated model): at 16 waves the per-step budget
// ~1735cyc was ~1/3 DS-pipe (192 b128 wave-ops on ONE LDS pipe/CU), ~1/3
// issue, ~1/3 barrier+latency. CD's th4/ti4 reads are j-independent, so one
// 8-read set feeds 2 outputs: DS wave-ops/step 192 -> 96; barrier
// participants 16 -> 8; issue/SIMD ~560 -> ~424 cyc.
//  AB: u0 = 4w+(lane>>4), u1 = u0+32; sub = lane&15; two interleaved DPP
//      reduce chains; sub==15 writes t2hS[u0], t2hS[u1] (same-bank pair but
//      separate ops, 4 active lanes each, 4-way max).
//  CD: g = lane&3, jj = lane>>2, j0 = 16w+jj, j1 = j0+128. Shared th/ti
//      reads; two activation chains; quad bcast serves both j's.
// hS transposed layout unchanged: h[j] at word 64*((j&15)>>2)+4*(j>>4)+(j&3)
// -> AB reads hS4[kk*16+sub] bank-base 4*sub mod 32 = true 2-way (free).
__global__ __launch_bounds__(512, 2) void k_lstm(const float* __restrict__ ws,
                                                 const float* __restrict__ T2,
                                                 float* __restrict__ out) {
    __shared__ __align__(16) float hS[256];
    __shared__ __align__(16) float t2hS[64];
    __shared__ __align__(16) float t2iS[2][64];

    const int tid  = threadIdx.x;
    const int w    = tid >> 6;                          // 0..7
    const int lane = tid & 63;
    const int b    = blockIdx.x;

    // ---- AB weights: rows u0 and u1 = u0+32 of A1h, cols sub*16..+15 ----
    const int uab = 4 * w + (lane >> 4);                // 0..31
    const int sub = lane & 15;
    v2f a1p0[8], a1p1[8];
    {
        const float4* A1h4 = (const float4*)(ws + WS_A1H);
#pragma unroll
        for (int kk = 0; kk < 4; ++kk) {
            float4 v0 = A1h4[uab * 64 + sub * 4 + kk];
            float4 v1 = A1h4[(uab + 32) * 64 + sub * 4 + kk];
            a1p0[2 * kk + 0] = (v2f){v0.x, v0.y};
            a1p0[2 * kk + 1] = (v2f){v0.z, v0.w};
            a1p1[2 * kk + 0] = (v2f){v1.x, v1.y};
            a1p1[2 * kk + 1] = (v2f){v1.z, v1.w};
        }
    }

    // ---- CD weights: g=lane&3, jj=lane>>2, j0=16w+jj, j1=j0+128 ----
    const int jj = lane >> 2;                           // 0..15
    const int g  = lane & 3;
    const int j0 = 16 * w + jj;                         // 0..127
    const int j1 = j0 + 128;                            // 128..255
    v2f c2hp0[8], c2ip0[8], c2hp1[8], c2ip1[8];
#pragma unroll
    for (int qq = 0; qq < 4; ++qq) {
#pragma unroll
        for (int hh = 0; hh < 2; ++hh) {
            int s0 = 16 * g + 4 * qq + 2 * hh;
            c2hp0[2 * qq + hh] = (v2f){ws[WS_C2H + (s0 + 0) * 256 + j0],
                                       ws[WS_C2H + (s0 + 1) * 256 + j0]};
            c2ip0[2 * qq + hh] = (v2f){ws[WS_C2I + (s0 + 0) * 256 + j0],
                                       ws[WS_C2I + (s0 + 1) * 256 + j0]};
            c2hp1[2 * qq + hh] = (v2f){ws[WS_C2H + (s0 + 0) * 256 + j1],
                                       ws[WS_C2H + (s0 + 1) * 256 + j1]};
            c2ip1[2 * qq + hh] = (v2f){ws[WS_C2I + (s0 + 0) * 256 + j1],
                                       ws[WS_C2I + (s0 + 1) * 256 + j1]};
        }
    }
    float bias0 = ws[WS_BIAS + g * 256 + j0];
    float bias1 = ws[WS_BIAS + g * 256 + j1];
    const float am = (g == 2) ? 2.0f : 1.0f;            // tanh vs sigmoid
    const float as = 1.442695040888963f * am;

#pragma unroll
    for (int i = 0; i < 8; ++i)
        asm volatile("" : "+v"(a1p0[i]), "+v"(a1p1[i]), "+v"(c2hp0[i]),
                         "+v"(c2ip0[i]), "+v"(c2hp1[i]), "+v"(c2ip1[i]));

    // transposed hS slots: h[j] at word 64*((j&15)>>2) + 4*(j>>4) + (j&3)
    const int hw0 = ((jj >> 2) << 6) + 4 * w + (jj & 3);
    const int hw1 = hw0 + 32;                           // j1: j>>4 = w+8

    float c0 = 0.f, c1 = 0.f, h0l = 0.f, h1l = 0.f;
    if (tid < 256) hS[tid] = 0.f;
    const float* T2b = T2 + (long)b * 1024 * 64;
    const float4* T2b4 = (const float4*)T2b;
    float4 preA = make_float4(0.f, 0.f, 0.f, 0.f);
    float4 preB = make_float4(0.f, 0.f, 0.f, 0.f);
    if (tid < 16) {
        ((float4*)t2iS[0])[tid] = T2b4[tid];
        preA = T2b4[16 + tid];                          // T2[t=1]
    }
    bar_lds();

    float* outB = out + (long)b * 1024 * 256;
    const float4* hS4 = (const float4*)hS;
    const float4* th4 = (const float4*)t2hS;

    auto body = [&](int t, float4& preW, float4& preL) {
        // ---- AB (packed, 2 u-rows) ----
        v2f sA0 = (v2f){0.f, 0.f}, sB0 = (v2f){0.f, 0.f};
        v2f sA1 = (v2f){0.f, 0.f}, sB1 = (v2f){0.f, 0.f};
#pragma unroll
        for (int kk = 0; kk < 4; ++kk) {
            float4 hv = hS4[kk * 16 + sub];             // 2-way bcast, free
            v2f hxy = (v2f){hv.x, hv.y}, hzw = (v2f){hv.z, hv.w};
            sA0 = pk_fma(hxy, a1p0[2 * kk + 0], sA0);
            sB0 = pk_fma(hzw, a1p0[2 * kk + 1], sB0);
            sA1 = pk_fma(hxy, a1p1[2 * kk + 0], sA1);
            sB1 = pk_fma(hzw, a1p1[2 * kk + 1], sB1);
        }
        float tv0 = (sA0.x + sA0.y) + (sB0.x + sB0.y);
        float tv1 = (sA1.x + sA1.y) + (sB1.x + sB1.y);
        // stage next t2i + prefetch (independent; overlaps DPP chains)
        if ((tid < 16) && (t + 1 < 1024))
            ((float4*)t2iS[(t + 1) & 1])[tid] = preW;
        if ((tid < 16) && (t + 2 < 1024))
            preL = T2b4[(t + 2) * 16 + tid];
        // two interleaved DPP sums over the 16-lane row -> totals in sub==15
        tv0 = dpp_add<0x111>(tv0);  tv1 = dpp_add<0x111>(tv1);
        tv0 = dpp_add<0x112>(tv0);  tv1 = dpp_add<0x112>(tv1);
        tv0 = dpp_add<0x114>(tv0);  tv1 = dpp_add<0x114>(tv1);
        tv0 = dpp_add<0x118>(tv0);  tv1 = dpp_add<0x118>(tv1);
        if (sub == 15) {
            t2hS[uab]      = tv0;
            t2hS[uab + 32] = tv1;
        }

        bar_lds();  // 1: t2hS + t2iS[(t+1)&1] ready

        // ---- CD + cell: shared th/ti reads feed both j0 and j1 ----
        const float4* ti4 = (const float4*)t2iS[t & 1];
        v2f aH0 = (v2f){bias0, 0.f}, aL0 = (v2f){0.f, 0.f};
        v2f aH1 = (v2f){bias1, 0.f}, aL1 = (v2f){0.f, 0.f};
#pragma unroll
        for (int qq = 0; qq < 4; ++qq) {
            float4 th = th4[g * 4 + qq];                // 2-way bcast, free
            float4 ti = ti4[g * 4 + qq];
            v2f txy = (v2f){th.x, th.y}, tzw = (v2f){th.z, th.w};
            v2f ixy = (v2f){ti.x, ti.y}, izw = (v2f){ti.z, ti.w};
            aH0 = pk_fma(txy, c2hp0[2 * qq + 0], aH0);
            aL0 = pk_fma(tzw, c2hp0[2 * qq + 1], aL0);
            aH1 = pk_fma(txy, c2hp1[2 * qq + 0], aH1);
            aL1 = pk_fma(tzw, c2hp1[2 * qq + 1], aL1);
            aH0 = pk_fma(ixy, c2ip0[2 * qq + 0], aH0);
            aL0 = pk_fma(izw, c2ip0[2 * qq + 1], aL0);
            aH1 = pk_fma(ixy, c2ip1[2 * qq + 0], aH1);
            aL1 = pk_fma(izw, c2ip1[2 * qq + 1], aL1);
        }
        float acc0 = (aH0.x + aH0.y) + (aL0.x + aL0.y);
        float acc1 = (aH1.x + aH1.y) + (aL1.x + aL1.y);
        // unified activation: sigmoid(x)=1-1/(1+e^x), tanh(x)=1-2/(1+e^2x)
        float e0   = __builtin_amdgcn_exp2f(as * acc0);
        float e1   = __builtin_amdgcn_exp2f(as * acc1);
        float act0 = 1.0f - am * __builtin_amdgcn_rcpf(1.0f + e0);
        float act1 = 1.0f - am * __builtin_amdgcn_rcpf(1.0f + e1);
        // gather i,f,g,o within the quad via DPP broadcasts (serves both j)
        float gi0 = dpp_bcast<0x00>(act0), gi1 = dpp_bcast<0x00>(act1);
        float gf0 = dpp_bcast<0x55>(act0), gf1 = dpp_bcast<0x55>(act1);
        float gg0 = dpp_bcast<0xAA>(act0), gg1 = dpp_bcast<0xAA>(act1);
        float go0 = dpp_bcast<0xFF>(act0), go1 = dpp_bcast<0xFF>(act1);
        c0 = gf0 * c0 + gi0 * gg0;
        c1 = gf1 * c1 + gi1 * gg1;
        float ex0 = __builtin_amdgcn_exp2f(2.885390081777926f * c0);
        float ex1 = __builtin_amdgcn_exp2f(2.885390081777926f * c1);
        float th0 = 1.0f - 2.0f * __builtin_amdgcn_rcpf(1.0f + ex0);
        float th1 = 1.0f - 2.0f * __builtin_amdgcn_rcpf(1.0f + ex1);
        float h0 = go0 * th0;
        float h1 = go1 * th1;
        h0l = h0; h1l = h1;
        if (g == 0) {
            hS[hw0] = h0;                               // 4-way write, ~free
            hS[hw1] = h1;
            outB[t * 256 + j0] = h0;                    // never drained
            outB[t * 256 + j1] = h1;
        }

        bar_lds();  // 2: hS ready for next AB
    };

    for (int t = 0; t < 1024; t += 2) {
        body(t, preA, preB);
        body(t + 1, preB, preA);
    }

    if (g == 0) {
        out[16777216 + b * 256 + j0] = h0l;
        out[16777216 + b * 256 + j1] = h1l;
        out[16777216 + 16384 + b * 256 + j0] = c0;
        out[16777216 + 16384 + b * 256 + j1] = c1;
    }
}

extern "C" void kernel_launch(void* const* d_in, const int* in_sizes, int n_in,
                              void* d_out, int out_size, void* d_ws, size_t ws_size,
                              hipStream_t stream) {
    const float* x     = (const float*)d_in[0];
    const float* ih_g0 = (const float*)d_in[1];
    const float* ih_g1 = (const float*)d_in[2];
    const float* ih_g2 = (const float*)d_in[3];
    const float* ih_g3 = (const float*)d_in[4];
    const float* ih_b  = (const float*)d_in[5];
    const float* hh_g0 = (const float*)d_in[6];
    const float* hh_g1 = (const float*)d_in[7];
    const float* hh_g2 = (const float*)d_in[8];
    const float* hh_g3 = (const float*)d_in[9];
    const float* hh_b  = (const float*)d_in[10];
    float* out = (float*)d_out;
    float* ws  = (float*)d_ws;

    k_compose<<<132, 256, 0, stream>>>(ih_g0, ih_g1, ih_g2, ih_g3, ih_b,
                                       hh_g0, hh_g1, hh_g2, hh_g3, hh_b, ws);
    k_t2ih<<<1024, 256, 0, stream>>>(x, ws, ws + WS_T2);
    k_lstm<<<64, 512, 0, stream>>>(ws, ws + WS_T2, out);
}